// Round 2
// baseline (1102.865 us; speedup 1.0000x reference)
//
#include <hip/hip_runtime.h>
#include <math.h>

#define B_ 16
#define S_ 2048
#define D_ 1024
#define SCALE 0.03125f   // 1/sqrt(1024)

typedef __bf16 bf16;
typedef __bf16 bf16x4v __attribute__((ext_vector_type(4)));
typedef __bf16 bf16x8 __attribute__((ext_vector_type(8)));
typedef float f32x4 __attribute__((ext_vector_type(4)));

#define MFMA(a, b, c) __builtin_amdgcn_mfma_f32_16x16x32_bf16((a), (b), (c), 0, 0, 0)

// Raw barrier: drain LDS only; global loads stay in flight across it.
#define BAR()                                           \
  do {                                                  \
    asm volatile("s_waitcnt lgkmcnt(0)" ::: "memory");  \
    __builtin_amdgcn_s_barrier();                       \
    asm volatile("" ::: "memory");                      \
  } while (0)

// ---------------------------------------------------------------------------
// Prep: K,V fp32 [B][S][D] -> fragment-major bf16 Kr/Vr (same layout as R4),
// NO LDS round-trip.
//   K frag g (=f*64+l, f=kc*4+nt): 8 contiguous source elems of one row ->
//     direct float4 x2 load, each p-instruction reads 64 rows x 128B (full
//     cache lines).
//   V frag: true transpose -> 8 x 4B gathers (stride 4KB); lines fully
//     consumed across (nt, l&15) within the block via L1/L2.
// grid (32 jt, 8 w, 16 b), 256 thr; 4 frags of each per thread.
// ---------------------------------------------------------------------------
__global__ __launch_bounds__(256) void prep_kernel(const float* __restrict__ K,
                                                   const float* __restrict__ V,
                                                   bf16* __restrict__ Kr,
                                                   bf16* __restrict__ Vr) {
  const int jt = blockIdx.x, w = blockIdx.y, b = blockIdx.z;
  const int t = threadIdx.x;
  const size_t sbase = ((size_t)b * S_ + jt * 64) * D_ + w * 128;
  bf16* kd = Kr + (((size_t)b * 32 + jt) * 8 + w) * 8192;
  bf16* vd = Vr + (((size_t)b * 32 + jt) * 8 + w) * 8192;
#pragma unroll
  for (int p = 0; p < 4; ++p) {
    const int g = p * 256 + t;
    const int l = g & 63, f = g >> 6;
    const int kc = f >> 2, nt = f & 3;
    const float* sp = K + sbase + (size_t)(nt * 16 + (l & 15)) * D_ +
                      kc * 32 + (l >> 4) * 8;
    float4 a = *(const float4*)sp;
    float4 c = *(const float4*)(sp + 4);
    bf16x8 o;
    o[0] = (bf16)a.x; o[1] = (bf16)a.y; o[2] = (bf16)a.z; o[3] = (bf16)a.w;
    o[4] = (bf16)c.x; o[5] = (bf16)c.y; o[6] = (bf16)c.z; o[7] = (bf16)c.w;
    *(bf16x8*)(kd + (size_t)g * 8) = o;
  }
#pragma unroll
  for (int p = 0; p < 4; ++p) {
    const int g = p * 256 + t;
    const int l = g & 63, f = g >> 6;
    const int ks = f >> 3, nt = f & 7;
    const float* sp = V + sbase + (size_t)(ks * 32 + (l >> 4) * 8) * D_ +
                      nt * 16 + (l & 15);
    bf16x8 o;
#pragma unroll
    for (int j = 0; j < 8; ++j) o[j] = (bf16)sp[(size_t)j * D_];
    *(bf16x8*)(vd + (size_t)g * 8) = o;
  }
}

// ---------------------------------------------------------------------------
// Flash attention. 512 threads = 8 waves per (batch, 32-row Q tile); wave w
// owns d-slice [128w,128w+128).
//
// R5: (1) kf register double-buffer: kf for jt+1 issued during phase 1 of jt
// (a full ~10k-cycle iteration of slack) via 2-body unroll -- QK never waits
// on memory. (2) sc stored fragment-major: phase-1 spill is 8 ds_write_b128
// (was 32 scalar b32); phase 2 reads one f32x4 (4 rows x 1 col) per lane,
// 8-shfl in-register 4x4 transpose, then per-wave-owns-4-rows softmax with
// m/l in REGISTERS (no LDS stats round-trip, no divergent serial branch).
// Reduction trees identical to R4 -> bit-exact softmax. (3) setprio around
// MFMA clusters.
// ---------------------------------------------------------------------------
__global__ __launch_bounds__(512, 2) void attn_kernel(
    const float* __restrict__ Q, const bf16* __restrict__ Kr,
    const bf16* __restrict__ Vr, const int* __restrict__ mask,
    float* __restrict__ out) {
  __shared__ f32x4 scv[8][8][64];  // [wave][frag mt*4+nt][lane] -- 64 KiB
  __shared__ bf16 pbuf[32][72];    // P tile (pitch 72: 16B-aligned rows)
  __shared__ float alphaS[32], lS[32];

  const int d = blockIdx.x;
  const int b = ((d & 7) << 1) | ((d >> 3) & 1);  // batch -> XCD pinning
  const int q0 = (d >> 4) * 32;
  const int t = threadIdx.x;
  const int w = t >> 6;          // wave 0..7
  const int lane = t & 63;
  const int n16 = lane & 15;
  const int q4 = lane >> 4;      // quad 0..3
  const int ds0 = w * 128;       // this wave's d-slice

  const float* Qb = Q + (size_t)b * S_ * D_;
  const bf16* Kw = Kr + ((size_t)b * 256 + w) * 8192 + (size_t)lane * 8;
  const bf16* Vw = Vr + ((size_t)b * 256 + w) * 8192 + (size_t)lane * 8;

  // phase-2 row ownership: wave w reduces rows 4w..4w+3; this lane ends up
  // holding row prow = 4w + (lane&3) after the in-register transpose.
  const int prow = 4 * w + (lane & 3);
  const float ma = mask[b * S_ + q0 + prow] ? 0.0f : 1e9f;
  float m_run = -1e30f, l_run = 0.0f;   // running max / denom (registers)

  // Q A-fragments (fp32 -> bf16), register resident: qf[mt][kc]
  bf16x8 qf[2][4];
#pragma unroll
  for (int mt = 0; mt < 2; ++mt)
#pragma unroll
    for (int kc = 0; kc < 4; ++kc) {
      const float* qp = Qb + (size_t)(q0 + 16 * mt + n16) * D_ +
                        ds0 + kc * 32 + q4 * 8;
      float4 a = *(const float4*)qp;
      float4 c = *(const float4*)(qp + 4);
      bf16x8 f;
      f[0] = (bf16)a.x; f[1] = (bf16)a.y; f[2] = (bf16)a.z; f[3] = (bf16)a.w;
      f[4] = (bf16)c.x; f[5] = (bf16)c.y; f[6] = (bf16)c.z; f[7] = (bf16)c.w;
      qf[mt][kc] = f;
    }

  // O accumulator: o[mt][nt][r] = O[16*mt + 4*q4 + r][ds0 + nt*16 + n16]
  f32x4 o[2][8];
#pragma unroll
  for (int mt = 0; mt < 2; ++mt)
#pragma unroll
    for (int nt = 0; nt < 8; ++nt) o[mt][nt] = (f32x4){0.f, 0.f, 0.f, 0.f};

  // prologue: kf for jt=0
  bf16x8 kfA[4][4], kfB[4][4];
#pragma unroll
  for (int kc = 0; kc < 4; ++kc)
#pragma unroll
    for (int nt = 0; nt < 4; ++nt)
      kfA[nt][kc] = *(const bf16x8*)(Kw + ((kc * 4 + nt) << 9));

  auto body = [&](int jt, bf16x8 (&kfC)[4][4], bf16x8 (&kfN)[4][4]) {
    // ---- phase 1: partial scores over this wave's 128-d slice
    f32x4 acc[2][4];
#pragma unroll
    for (int mt = 0; mt < 2; ++mt)
#pragma unroll
      for (int nt = 0; nt < 4; ++nt) acc[mt][nt] = (f32x4){0.f, 0.f, 0.f, 0.f};
    __builtin_amdgcn_s_setprio(1);
#pragma unroll
    for (int kc = 0; kc < 4; ++kc)
#pragma unroll
      for (int nt = 0; nt < 4; ++nt)
#pragma unroll
        for (int mt = 0; mt < 2; ++mt)
          acc[mt][nt] = MFMA(qf[mt][kc], kfC[nt][kc], acc[mt][nt]);
    __builtin_amdgcn_s_setprio(0);

    // spill partials fragment-major: 8 x ds_write_b128, lane-contiguous
#pragma unroll
    for (int mt = 0; mt < 2; ++mt)
#pragma unroll
      for (int nt = 0; nt < 4; ++nt) scv[w][mt * 4 + nt][lane] = acc[mt][nt];

    // early-issue V fragments for phase 3 (in flight across both barriers)
    const bf16* vb = Vw + (size_t)jt * 65536;
    bf16x8 vf[2][8];
#pragma unroll
    for (int ks = 0; ks < 2; ++ks)
#pragma unroll
      for (int nt = 0; nt < 8; ++nt)
        vf[ks][nt] = *(const bf16x8*)(vb + ((ks * 8 + nt) << 9));

    // prefetch next jt's K fragments (consumed next body -- ~10k cy slack)
    const bf16* kbn = Kw + (size_t)((jt + 1) & 31) * 65536;
#pragma unroll
    for (int kc = 0; kc < 4; ++kc)
#pragma unroll
      for (int nt = 0; nt < 4; ++nt)
        kfN[nt][kc] = *(const bf16x8*)(kbn + ((kc * 4 + nt) << 9));
    BAR();

    // ---- phase 2: cross-wave reduce + online softmax, wave w owns 4 rows
    {
      const int fsel = (w >> 2) * 4 + (lane >> 4);
      const int lidx = (w & 3) * 16 + n16;
      f32x4 s = scv[0][fsel][lidx];
#pragma unroll
      for (int ww = 1; ww < 8; ++ww) s += scv[ww][fsel][lidx];
      // in-register 4x4 transpose within lane groups of 4:
      // in: s[r] = Ssum[4w+r][lane]; out: s[j] = Ssum[prow][(lane&~3)+j]
      float t0, t1;
      t0 = (lane & 1) ? s[0] : s[1]; t0 = __shfl_xor(t0, 1);
      t1 = (lane & 1) ? s[2] : s[3]; t1 = __shfl_xor(t1, 1);
      s[0] = (lane & 1) ? t0 : s[0]; s[1] = (lane & 1) ? s[1] : t0;
      s[2] = (lane & 1) ? t1 : s[2]; s[3] = (lane & 1) ? s[3] : t1;
      t0 = (lane & 2) ? s[0] : s[2]; t0 = __shfl_xor(t0, 2);
      t1 = (lane & 2) ? s[1] : s[3]; t1 = __shfl_xor(t1, 2);
      s[0] = (lane & 2) ? t0 : s[0]; s[2] = (lane & 2) ? s[2] : t0;
      s[1] = (lane & 2) ? t1 : s[1]; s[3] = (lane & 2) ? s[3] : t1;
      // faithful fp32 order: (dot * scale) then subtract 1e9 -> bit-collapse
      s[0] = s[0] * SCALE - ma;
      s[1] = s[1] * SCALE - ma;
      s[2] = s[2] * SCALE - ma;
      s[3] = s[3] * SCALE - ma;
      float mx = fmaxf(fmaxf(s[0], s[1]), fmaxf(s[2], s[3]));
      mx = fmaxf(mx, __shfl_xor(mx, 4));
      mx = fmaxf(mx, __shfl_xor(mx, 8));
      mx = fmaxf(mx, __shfl_xor(mx, 16));
      mx = fmaxf(mx, __shfl_xor(mx, 32));
      const float m_new = fmaxf(m_run, mx);
      const float alpha = __expf(m_run - m_new);  // 0 on first chunk
      const float p0 = __expf(s[0] - m_new);
      const float p1 = __expf(s[1] - m_new);
      const float p2 = __expf(s[2] - m_new);
      const float p3 = __expf(s[3] - m_new);
      float ps = (p0 + p1) + (p2 + p3);
      ps += __shfl_xor(ps, 4);
      ps += __shfl_xor(ps, 8);
      ps += __shfl_xor(ps, 16);
      ps += __shfl_xor(ps, 32);
      l_run = l_run * alpha + ps;
      m_run = m_new;
      if (lane < 4) alphaS[4 * w + lane] = alpha;
      bf16x4v pk;
      pk[0] = (bf16)p0; pk[1] = (bf16)p1; pk[2] = (bf16)p2; pk[3] = (bf16)p3;
      *(bf16x4v*)&pbuf[prow][(lane >> 2) * 4] = pk;  // one 8B store
    }
    BAR();

    // ---- phase 3: rescale O by alpha, then O += P @ V_chunk
    f32x4 av[2];
#pragma unroll
    for (int mt = 0; mt < 2; ++mt)
#pragma unroll
      for (int rg = 0; rg < 4; ++rg) av[mt][rg] = alphaS[16 * mt + 4 * q4 + rg];
#pragma unroll
    for (int mt = 0; mt < 2; ++mt)
#pragma unroll
      for (int nt = 0; nt < 8; ++nt) o[mt][nt] *= av[mt];

    bf16x8 pf[2][2];  // P A-frags: P[16*mt + n16][ks*32 + q4*8 + 0..7]
#pragma unroll
    for (int mt = 0; mt < 2; ++mt)
#pragma unroll
      for (int ks = 0; ks < 2; ++ks)
        pf[mt][ks] = *(const bf16x8*)&pbuf[16 * mt + n16][ks * 32 + q4 * 8];

    __builtin_amdgcn_s_setprio(1);
#pragma unroll
    for (int ks = 0; ks < 2; ++ks)
#pragma unroll
      for (int nt = 0; nt < 8; ++nt)
#pragma unroll
        for (int mt = 0; mt < 2; ++mt)
          o[mt][nt] = MFMA(pf[mt][ks], vf[ks][nt], o[mt][nt]);
    __builtin_amdgcn_s_setprio(0);
  };

  for (int jt = 0; jt < 32; jt += 2) {
    body(jt, kfA, kfB);
    body(jt + 1, kfB, kfA);
  }

  // ---- epilogue: publish row sums, divide, store fp32
  if (lane < 4) lS[4 * w + lane] = l_run;
  BAR();
  f32x4 invl[2];
#pragma unroll
  for (int mt = 0; mt < 2; ++mt)
#pragma unroll
    for (int rg = 0; rg < 4; ++rg)
      invl[mt][rg] = 1.0f / lS[16 * mt + 4 * q4 + rg];
#pragma unroll
  for (int mt = 0; mt < 2; ++mt)
#pragma unroll
    for (int nt = 0; nt < 8; ++nt)
#pragma unroll
      for (int rg = 0; rg < 4; ++rg) {
        const size_t row = (size_t)b * S_ + q0 + 16 * mt + 4 * q4 + rg;
        out[row * D_ + ds0 + nt * 16 + n16] = o[mt][nt][rg] * invl[mt][rg];
      }
}

// ---------------------------------------------------------------------------
extern "C" void kernel_launch(void* const* d_in, const int* in_sizes, int n_in,
                              void* d_out, int out_size, void* d_ws, size_t ws_size,
                              hipStream_t stream) {
  (void)in_sizes; (void)n_in; (void)out_size; (void)ws_size;
  const float* Q = (const float*)d_in[0];
  const float* K = (const float*)d_in[1];
  const float* V = (const float*)d_in[2];
  const int* mask = (const int*)d_in[3];
  float* out = (float*)d_out;
  bf16* Kr = (bf16*)d_ws;                              // 64 MiB
  bf16* Vr = (bf16*)d_ws + (size_t)B_ * S_ * D_;       // next 64 MiB

  prep_kernel<<<dim3(32, 8, B_), 256, 0, stream>>>(K, V, Kr, Vr);
  attn_kernel<<<B_ * (S_ / 32), 512, 0, stream>>>(Q, Kr, Vr, mask, out);
}